// Round 5
// baseline (117.082 us; speedup 1.0000x reference)
//
#include <hip/hip_runtime.h>
#include <stdint.h>

#define B_ 16
#define N_ 256
#define T_ 128
#define K_ 128
#define H_ 16
#define G_ 1024                 // interpolation grid points
#define NELEM (B_*N_*N_)        // 1048576
#define NPART 1024              // partial min/max pairs

typedef float f32x4 __attribute__((ext_vector_type(4)));  // native vec for nt-store

// ---- order-preserving float<->uint encoding for min/max reduction ----
__device__ __forceinline__ uint32_t enc_f32(float f) {
    uint32_t u = __float_as_uint(f);
    return (u & 0x80000000u) ? ~u : (u | 0x80000000u);
}
__device__ __forceinline__ float dec_f32(uint32_t u) {
    uint32_t b = (u & 0x80000000u) ? (u ^ 0x80000000u) : ~u;
    return __uint_as_float(b);
}
__device__ __forceinline__ float fix_nonfinite(float v) {
    // nan_to_num(nan=0, posinf=0, neginf=0)
    uint32_t u = __float_as_uint(v);
    return ((u & 0x7F800000u) == 0x7F800000u) ? 0.0f : v;
}

// ---- kernel 1: per-block min/max partials of s = gamma*d + beta (NO atomics) ----
// 1024 blocks x 256 threads, one float4 of d per thread (no serial loop).
__global__ __launch_bounds__(256) void k_partial(
        const float4* __restrict__ d4, const int* __restrict__ tokens,
        const float* __restrict__ gamma_t, const float* __restrict__ beta_t,
        uint32_t* __restrict__ pmin, uint32_t* __restrict__ pmax) {
    int idx = blockIdx.x * 256 + threadIdx.x;   // float4 index
    int e0 = idx << 2;
    int b = e0 >> 16, n = (e0 >> 8) & 255, m0 = e0 & 255;
    float4 dv = d4[idx];
    int ti = tokens[(b << 8) + n];
    int4 tj = *(const int4*)&tokens[(b << 8) + m0];
    const float* grow = gamma_t + ti * T_;
    const float* brow = beta_t  + ti * T_;
    float s0 = fmaf(grow[tj.x], fix_nonfinite(dv.x), brow[tj.x]);
    float s1 = fmaf(grow[tj.y], fix_nonfinite(dv.y), brow[tj.y]);
    float s2 = fmaf(grow[tj.z], fix_nonfinite(dv.z), brow[tj.z]);
    float s3 = fmaf(grow[tj.w], fix_nonfinite(dv.w), brow[tj.w]);
    uint32_t u0 = enc_f32(s0), u1 = enc_f32(s1);
    uint32_t u2 = enc_f32(s2), u3 = enc_f32(s3);
    uint32_t lmin = min(min(u0, u1), min(u2, u3));
    uint32_t lmax = max(max(u0, u1), max(u2, u3));
    #pragma unroll
    for (int off = 32; off > 0; off >>= 1) {
        lmin = min(lmin, (uint32_t)__shfl_down((unsigned int)lmin, off, 64));
        lmax = max(lmax, (uint32_t)__shfl_down((unsigned int)lmax, off, 64));
    }
    __shared__ uint32_t wmin[4], wmax[4];
    int wave = threadIdx.x >> 6;
    if ((threadIdx.x & 63) == 0) { wmin[wave] = lmin; wmax[wave] = lmax; }
    __syncthreads();
    if (threadIdx.x == 0) {
        pmin[blockIdx.x] = min(min(wmin[0], wmin[1]), min(wmin[2], wmin[3]));
        pmax[blockIdx.x] = max(max(wmax[0], wmax[1]), max(wmax[2], wmax[3]));
    }
}

// ---- kernel 2: fused (reduce 1024 partials) + tabulate f(s) on the grid ----
__global__ __launch_bounds__(128) void k_table(
        const uint32_t* __restrict__ pmin, const uint32_t* __restrict__ pmax,
        const float* __restrict__ mu, const float* __restrict__ log_sigma,
        const float* __restrict__ W1, const float* __restrict__ b1,
        const float* __restrict__ W2, const float* __restrict__ b2,
        float* __restrict__ table, float* __restrict__ mmf) {
    __shared__ float psi[K_];
    __shared__ float hv[K_];
    __shared__ uint32_t wmin[2], wmax[2];
    int t = threadIdx.x;

    // every block redundantly folds the 1024 partial pairs (L2-hit, cheap)
    uint32_t lmin = 0xFFFFFFFFu, lmax = 0u;
    #pragma unroll
    for (int i = 0; i < 8; i++) {
        lmin = min(lmin, pmin[t + 128 * i]);
        lmax = max(lmax, pmax[t + 128 * i]);
    }
    #pragma unroll
    for (int off = 32; off > 0; off >>= 1) {
        lmin = min(lmin, (uint32_t)__shfl_down((unsigned int)lmin, off, 64));
        lmax = max(lmax, (uint32_t)__shfl_down((unsigned int)lmax, off, 64));
    }
    if ((t & 63) == 0) { wmin[t >> 6] = lmin; wmax[t >> 6] = lmax; }
    __syncthreads();
    float smin = dec_f32(min(wmin[0], wmin[1]));
    float smax = dec_f32(max(wmax[0], wmax[1]));
    if (blockIdx.x == 0 && t == 0) { mmf[0] = smin; mmf[1] = smax; }

    float s = smin + (smax - smin) * ((float)blockIdx.x / (float)(G_ - 1));
    float ls  = log_sigma[t];
    float sig = fmaxf(ls, 0.0f) + log1pf(expf(-fabsf(ls))) + 1e-6f; // softplus + 1e-6
    float x   = (s - mu[t]) / sig;
    psi[t] = expf(-0.5f * x * x) / (2.5066282746310002f * sig);  // /(sqrt(2pi)*sig)
    __syncthreads();
    float acc = b1[t];
    #pragma unroll 8
    for (int k = 0; k < K_; k++) acc = fmaf(psi[k], W1[k * K_ + t], acc);
    hv[t] = fmaxf(acc, 0.0f);
    __syncthreads();
    if (t < H_) {
        float a2 = b2[t];
        #pragma unroll 8
        for (int j = 0; j < K_; j++) a2 = fmaf(hv[j], W2[j * H_ + t], a2);
        table[blockIdx.x * H_ + t] = a2;
    }
}

// ---- kernel 3: main — table + gamma/beta rows in LDS, nontemporal float4 out ----
__global__ __launch_bounds__(512) void k_main(
        const float4* __restrict__ d4, const int* __restrict__ tokens,
        const float* __restrict__ gamma_t, const float* __restrict__ beta_t,
        const float* __restrict__ mmf, const float4* __restrict__ tg,
        float* __restrict__ out) {
    __shared__ float4 tab[G_ * 4];      // 64 KB: grid row i -> tab[4i..4i+3]
    __shared__ float  grow_lds[8 * K_]; // 4 KB: gamma rows for this block's 8 n
    __shared__ float  brow_lds[8 * K_]; // 4 KB: beta rows
    int tid = threadIdx.x;

    // global loads issued FIRST so their latency overlaps the table staging
    int idx = blockIdx.x * 512 + tid;      // float4 index, one per thread
    int e0 = idx << 2;
    int base_e = blockIdx.x * 2048;        // first element of this block
    int b  = base_e >> 16;                 // batch (uniform in block)
    int n0 = (base_e >> 8) & 255;          // first n-row (block spans 8 rows)
    int m0 = e0 & 255;
    float4 dv = d4[idx];
    int4 tj = *(const int4*)&tokens[(b << 8) + m0];
    float smin  = mmf[0];
    float range = mmf[1] - smin;

    #pragma unroll
    for (int i = 0; i < 8; i++) tab[tid + i * 512] = tg[tid + i * 512];

    if (tid < 256) {
        int r  = tid >> 5;                 // row 0..7
        int c4 = (tid & 31) << 2;          // col 0,4,...,124
        int ti = tokens[(b << 8) + n0 + r];
        *(float4*)&grow_lds[r * K_ + c4] = *(const float4*)&gamma_t[ti * T_ + c4];
    } else {
        int t2 = tid - 256;
        int r  = t2 >> 5;
        int c4 = (t2 & 31) << 2;
        int ti = tokens[(b << 8) + n0 + r];
        *(float4*)&brow_lds[r * K_ + c4] = *(const float4*)&beta_t[ti * T_ + c4];
    }

    float invd = (range > 1e-30f) ? (float)(G_ - 1) / range : 0.0f;
    __syncthreads();

    int w = tid >> 6;                      // n-row within block (wave-uniform)
    const float* gr = &grow_lds[w * K_];
    const float* br = &brow_lds[w * K_];

    float s[4];
    s[0] = fmaf(gr[tj.x], fix_nonfinite(dv.x), br[tj.x]);
    s[1] = fmaf(gr[tj.y], fix_nonfinite(dv.y), br[tj.y]);
    s[2] = fmaf(gr[tj.z], fix_nonfinite(dv.z), br[tj.z]);
    s[3] = fmaf(gr[tj.w], fix_nonfinite(dv.w), br[tj.w]);

    int   i0[4];
    float fr[4];
    #pragma unroll
    for (int c = 0; c < 4; c++) {
        float tpos = (s[c] - smin) * invd;
        tpos = fminf(fmaxf(tpos, 0.0f), (float)(G_ - 1));
        int i = (int)tpos;
        if (i > G_ - 2) i = G_ - 2;
        i0[c] = i;
        fr[c] = tpos - (float)i;
    }

    // out[b][h][n][m0..m0+3]; base = b*H*N*N + n*N + m0
    size_t base = ((size_t)b << 20) | (uint32_t)(e0 & 0xFFFF);

    #pragma unroll
    for (int hq = 0; hq < 4; hq++) {       // h-quad: h = 4*hq .. 4*hq+3
        float4 P[4];
        #pragma unroll
        for (int c = 0; c < 4; c++) {
            float4 A  = tab[i0[c] * 4 + hq];
            float4 Bv = tab[i0[c] * 4 + 4 + hq];
            P[c].x = fmaf(fr[c], Bv.x - A.x, A.x);
            P[c].y = fmaf(fr[c], Bv.y - A.y, A.y);
            P[c].z = fmaf(fr[c], Bv.z - A.z, A.z);
            P[c].w = fmaf(fr[c], Bv.w - A.w, A.w);
        }
        f32x4 o0 = { P[0].x, P[1].x, P[2].x, P[3].x };
        f32x4 o1 = { P[0].y, P[1].y, P[2].y, P[3].y };
        f32x4 o2 = { P[0].z, P[1].z, P[2].z, P[3].z };
        f32x4 o3 = { P[0].w, P[1].w, P[2].w, P[3].w };
        // streaming stores: written once, never re-read — keep them out of L2
        __builtin_nontemporal_store(o0, (f32x4*)&out[base + (size_t)(hq * 4 + 0) * (N_ * N_)]);
        __builtin_nontemporal_store(o1, (f32x4*)&out[base + (size_t)(hq * 4 + 1) * (N_ * N_)]);
        __builtin_nontemporal_store(o2, (f32x4*)&out[base + (size_t)(hq * 4 + 2) * (N_ * N_)]);
        __builtin_nontemporal_store(o3, (f32x4*)&out[base + (size_t)(hq * 4 + 3) * (N_ * N_)]);
    }
}

extern "C" void kernel_launch(void* const* d_in, const int* in_sizes, int n_in,
                              void* d_out, int out_size, void* d_ws, size_t ws_size,
                              hipStream_t stream) {
    const float* d_mat     = (const float*)d_in[0];
    const int*   tokens    = (const int*)  d_in[1];
    const float* mu        = (const float*)d_in[2];
    const float* log_sigma = (const float*)d_in[3];
    const float* W1        = (const float*)d_in[4];
    const float* b1        = (const float*)d_in[5];
    const float* W2        = (const float*)d_in[6];
    const float* b2        = (const float*)d_in[7];
    const float* gamma_t   = (const float*)d_in[8];
    const float* beta_t    = (const float*)d_in[9];
    float* out = (float*)d_out;

    float*    mmf   = (float*)d_ws;                      // [smin, smax]
    uint32_t* pmin  = (uint32_t*)d_ws + 64;              // 1024 partial mins (enc)
    uint32_t* pmax  = (uint32_t*)d_ws + 64 + NPART;      // 1024 partial maxs (enc)
    float*    table = (float*)d_ws + 64 + 2 * NPART;     // G_*H_ floats (64 KB), 16B-aligned

    k_partial<<<NPART, 256, 0, stream>>>((const float4*)d_mat, tokens, gamma_t, beta_t,
                                         pmin, pmax);
    k_table<<<G_, 128, 0, stream>>>(pmin, pmax, mu, log_sigma, W1, b1, W2, b2,
                                    table, mmf);
    k_main<<<512, 512, 0, stream>>>((const float4*)d_mat, tokens, gamma_t, beta_t,
                                    mmf, (const float4*)table, out);
}

// Round 7
// 113.437 us; speedup vs baseline: 1.0321x; 1.0321x over previous
//
#include <hip/hip_runtime.h>
#include <stdint.h>

#define B_ 16
#define N_ 256
#define T_ 128
#define K_ 128
#define H_ 16
#define G_ 1024                 // interpolation grid points
#define NELEM (B_*N_*N_)        // 1048576
#define NPART 1024              // partial min/max pairs

// ---- order-preserving float<->uint encoding for min/max reduction ----
__device__ __forceinline__ uint32_t enc_f32(float f) {
    uint32_t u = __float_as_uint(f);
    return (u & 0x80000000u) ? ~u : (u | 0x80000000u);
}
__device__ __forceinline__ float dec_f32(uint32_t u) {
    uint32_t b = (u & 0x80000000u) ? (u ^ 0x80000000u) : ~u;
    return __uint_as_float(b);
}
__device__ __forceinline__ float fix_nonfinite(float v) {
    // nan_to_num(nan=0, posinf=0, neginf=0)
    uint32_t u = __float_as_uint(v);
    return ((u & 0x7F800000u) == 0x7F800000u) ? 0.0f : v;
}

// ---- kernel 1: per-block min/max partials of s = gamma*d + beta (NO atomics) ----
// 1024 blocks x 256 threads, one float4 of d per thread (no serial loop).
__global__ __launch_bounds__(256) void k_partial(
        const float4* __restrict__ d4, const int* __restrict__ tokens,
        const float* __restrict__ gamma_t, const float* __restrict__ beta_t,
        uint32_t* __restrict__ pmin, uint32_t* __restrict__ pmax) {
    int idx = blockIdx.x * 256 + threadIdx.x;   // float4 index
    int e0 = idx << 2;
    int b = e0 >> 16, n = (e0 >> 8) & 255, m0 = e0 & 255;
    float4 dv = d4[idx];
    int ti = tokens[(b << 8) + n];
    int4 tj = *(const int4*)&tokens[(b << 8) + m0];
    const float* grow = gamma_t + ti * T_;
    const float* brow = beta_t  + ti * T_;
    float s0 = fmaf(grow[tj.x], fix_nonfinite(dv.x), brow[tj.x]);
    float s1 = fmaf(grow[tj.y], fix_nonfinite(dv.y), brow[tj.y]);
    float s2 = fmaf(grow[tj.z], fix_nonfinite(dv.z), brow[tj.z]);
    float s3 = fmaf(grow[tj.w], fix_nonfinite(dv.w), brow[tj.w]);
    uint32_t u0 = enc_f32(s0), u1 = enc_f32(s1);
    uint32_t u2 = enc_f32(s2), u3 = enc_f32(s3);
    uint32_t lmin = min(min(u0, u1), min(u2, u3));
    uint32_t lmax = max(max(u0, u1), max(u2, u3));
    #pragma unroll
    for (int off = 32; off > 0; off >>= 1) {
        lmin = min(lmin, (uint32_t)__shfl_down((unsigned int)lmin, off, 64));
        lmax = max(lmax, (uint32_t)__shfl_down((unsigned int)lmax, off, 64));
    }
    __shared__ uint32_t wmin[4], wmax[4];
    int wave = threadIdx.x >> 6;
    if ((threadIdx.x & 63) == 0) { wmin[wave] = lmin; wmax[wave] = lmax; }
    __syncthreads();
    if (threadIdx.x == 0) {
        pmin[blockIdx.x] = min(min(wmin[0], wmin[1]), min(wmin[2], wmin[3]));
        pmax[blockIdx.x] = max(max(wmax[0], wmax[1]), max(wmax[2], wmax[3]));
    }
}

// ---- kernel 2: fused (reduce 1024 partials) + tabulate f(s) on the grid ----
__global__ __launch_bounds__(128) void k_table(
        const uint32_t* __restrict__ pmin, const uint32_t* __restrict__ pmax,
        const float* __restrict__ mu, const float* __restrict__ log_sigma,
        const float* __restrict__ W1, const float* __restrict__ b1,
        const float* __restrict__ W2, const float* __restrict__ b2,
        float* __restrict__ table, float* __restrict__ mmf) {
    __shared__ float psi[K_];
    __shared__ float hv[K_];
    __shared__ uint32_t wmin[2], wmax[2];
    int t = threadIdx.x;

    // every block redundantly folds the 1024 partial pairs (L2-hit, cheap)
    uint32_t lmin = 0xFFFFFFFFu, lmax = 0u;
    #pragma unroll
    for (int i = 0; i < 8; i++) {
        lmin = min(lmin, pmin[t + 128 * i]);
        lmax = max(lmax, pmax[t + 128 * i]);
    }
    #pragma unroll
    for (int off = 32; off > 0; off >>= 1) {
        lmin = min(lmin, (uint32_t)__shfl_down((unsigned int)lmin, off, 64));
        lmax = max(lmax, (uint32_t)__shfl_down((unsigned int)lmax, off, 64));
    }
    if ((t & 63) == 0) { wmin[t >> 6] = lmin; wmax[t >> 6] = lmax; }
    __syncthreads();
    float smin = dec_f32(min(wmin[0], wmin[1]));
    float smax = dec_f32(max(wmax[0], wmax[1]));
    if (blockIdx.x == 0 && t == 0) { mmf[0] = smin; mmf[1] = smax; }

    float s = smin + (smax - smin) * ((float)blockIdx.x / (float)(G_ - 1));
    float ls  = log_sigma[t];
    float sig = fmaxf(ls, 0.0f) + log1pf(expf(-fabsf(ls))) + 1e-6f; // softplus + 1e-6
    float x   = (s - mu[t]) / sig;
    psi[t] = expf(-0.5f * x * x) / (2.5066282746310002f * sig);  // /(sqrt(2pi)*sig)
    __syncthreads();
    float acc = b1[t];
    #pragma unroll 8
    for (int k = 0; k < K_; k++) acc = fmaf(psi[k], W1[k * K_ + t], acc);
    hv[t] = fmaxf(acc, 0.0f);
    __syncthreads();
    if (t < H_) {
        float a2 = b2[t];
        #pragma unroll 8
        for (int j = 0; j < K_; j++) a2 = fmaf(hv[j], W2[j * H_ + t], a2);
        table[blockIdx.x * H_ + t] = a2;
    }
}

// ---- kernel 3: main — table + gamma/beta rows in LDS, float4 I/O ----
__global__ __launch_bounds__(512) void k_main(
        const float4* __restrict__ d4, const int* __restrict__ tokens,
        const float* __restrict__ gamma_t, const float* __restrict__ beta_t,
        const float* __restrict__ mmf, const float4* __restrict__ tg,
        float* __restrict__ out) {
    __shared__ float4 tab[G_ * 4];      // 64 KB: grid row i -> tab[4i..4i+3]
    __shared__ float  grow_lds[8 * K_]; // 4 KB: gamma rows for this block's 8 n
    __shared__ float  brow_lds[8 * K_]; // 4 KB: beta rows
    int tid = threadIdx.x;

    // global loads issued FIRST so their latency overlaps the table staging
    int idx = blockIdx.x * 512 + tid;      // float4 index, one per thread
    int e0 = idx << 2;
    int base_e = blockIdx.x * 2048;        // first element of this block
    int b  = base_e >> 16;                 // batch (uniform in block)
    int n0 = (base_e >> 8) & 255;          // first n-row (block spans 8 rows)
    int m0 = e0 & 255;
    float4 dv = d4[idx];
    int4 tj = *(const int4*)&tokens[(b << 8) + m0];
    float smin  = mmf[0];
    float range = mmf[1] - smin;

    #pragma unroll
    for (int i = 0; i < 8; i++) tab[tid + i * 512] = tg[tid + i * 512];

    if (tid < 256) {
        int r  = tid >> 5;                 // row 0..7
        int c4 = (tid & 31) << 2;          // col 0,4,...,124
        int ti = tokens[(b << 8) + n0 + r];
        *(float4*)&grow_lds[r * K_ + c4] = *(const float4*)&gamma_t[ti * T_ + c4];
    } else {
        int t2 = tid - 256;
        int r  = t2 >> 5;
        int c4 = (t2 & 31) << 2;
        int ti = tokens[(b << 8) + n0 + r];
        *(float4*)&brow_lds[r * K_ + c4] = *(const float4*)&beta_t[ti * T_ + c4];
    }

    float invd = (range > 1e-30f) ? (float)(G_ - 1) / range : 0.0f;
    __syncthreads();

    int w = tid >> 6;                      // n-row within block (wave-uniform)
    const float* gr = &grow_lds[w * K_];
    const float* br = &brow_lds[w * K_];

    float s[4];
    s[0] = fmaf(gr[tj.x], fix_nonfinite(dv.x), br[tj.x]);
    s[1] = fmaf(gr[tj.y], fix_nonfinite(dv.y), br[tj.y]);
    s[2] = fmaf(gr[tj.z], fix_nonfinite(dv.z), br[tj.z]);
    s[3] = fmaf(gr[tj.w], fix_nonfinite(dv.w), br[tj.w]);

    int   i0[4];
    float fr[4];
    #pragma unroll
    for (int c = 0; c < 4; c++) {
        float tpos = (s[c] - smin) * invd;
        tpos = fminf(fmaxf(tpos, 0.0f), (float)(G_ - 1));
        int i = (int)tpos;
        if (i > G_ - 2) i = G_ - 2;
        i0[c] = i;
        fr[c] = tpos - (float)i;
    }

    // out[b][h][n][m0..m0+3]; base = b*H*N*N + n*N + m0
    size_t base = ((size_t)b << 20) | (uint32_t)(e0 & 0xFFFF);

    #pragma unroll
    for (int hq = 0; hq < 4; hq++) {       // h-quad: h = 4*hq .. 4*hq+3
        float4 P[4];
        #pragma unroll
        for (int c = 0; c < 4; c++) {
            float4 A  = tab[i0[c] * 4 + hq];
            float4 Bv = tab[i0[c] * 4 + 4 + hq];
            P[c].x = fmaf(fr[c], Bv.x - A.x, A.x);
            P[c].y = fmaf(fr[c], Bv.y - A.y, A.y);
            P[c].z = fmaf(fr[c], Bv.z - A.z, A.z);
            P[c].w = fmaf(fr[c], Bv.w - A.w, A.w);
        }
        float4 o0 = make_float4(P[0].x, P[1].x, P[2].x, P[3].x);
        float4 o1 = make_float4(P[0].y, P[1].y, P[2].y, P[3].y);
        float4 o2 = make_float4(P[0].z, P[1].z, P[2].z, P[3].z);
        float4 o3 = make_float4(P[0].w, P[1].w, P[2].w, P[3].w);
        *(float4*)&out[base + (size_t)(hq * 4 + 0) * (N_ * N_)] = o0;
        *(float4*)&out[base + (size_t)(hq * 4 + 1) * (N_ * N_)] = o1;
        *(float4*)&out[base + (size_t)(hq * 4 + 2) * (N_ * N_)] = o2;
        *(float4*)&out[base + (size_t)(hq * 4 + 3) * (N_ * N_)] = o3;
    }
}

extern "C" void kernel_launch(void* const* d_in, const int* in_sizes, int n_in,
                              void* d_out, int out_size, void* d_ws, size_t ws_size,
                              hipStream_t stream) {
    const float* d_mat     = (const float*)d_in[0];
    const int*   tokens    = (const int*)  d_in[1];
    const float* mu        = (const float*)d_in[2];
    const float* log_sigma = (const float*)d_in[3];
    const float* W1        = (const float*)d_in[4];
    const float* b1        = (const float*)d_in[5];
    const float* W2        = (const float*)d_in[6];
    const float* b2        = (const float*)d_in[7];
    const float* gamma_t   = (const float*)d_in[8];
    const float* beta_t    = (const float*)d_in[9];
    float* out = (float*)d_out;

    float*    mmf   = (float*)d_ws;                      // [smin, smax]
    uint32_t* pmin  = (uint32_t*)d_ws + 64;              // 1024 partial mins (enc)
    uint32_t* pmax  = (uint32_t*)d_ws + 64 + NPART;      // 1024 partial maxs (enc)
    float*    table = (float*)d_ws + 64 + 2 * NPART;     // G_*H_ floats (64 KB), 16B-aligned

    k_partial<<<NPART, 256, 0, stream>>>((const float4*)d_mat, tokens, gamma_t, beta_t,
                                         pmin, pmax);
    k_table<<<G_, 128, 0, stream>>>(pmin, pmax, mu, log_sigma, W1, b1, W2, b2,
                                    table, mmf);
    k_main<<<512, 512, 0, stream>>>((const float4*)d_mat, tokens, gamma_t, beta_t,
                                    mmf, (const float4*)table, out);
}